// Round 6
// baseline (462.656 us; speedup 1.0000x reference)
//
#include <hip/hip_runtime.h>
#include <stdint.h>

typedef __bf16 bf16x8 __attribute__((ext_vector_type(8)));
typedef float floatx4 __attribute__((ext_vector_type(4)));
typedef float floatx16 __attribute__((ext_vector_type(16)));

#define SB0 __builtin_amdgcn_sched_barrier(0)

__device__ __forceinline__ void gload_lds16(const void* g, void* l) {
    __builtin_amdgcn_global_load_lds((const __attribute__((address_space(1))) void*)g,
                                     (__attribute__((address_space(3))) void*)l, 16, 0, 0);
}

__device__ __forceinline__ uint16_t f2bf(float f) {
    uint32_t u = __float_as_uint(f);
    u += 0x7fff + ((u >> 16) & 1);   // RNE
    return (uint16_t)(u >> 16);
}
__device__ __forceinline__ uint32_t f2bf2(float lo, float hi) {
    return (uint32_t)f2bf(lo) | ((uint32_t)f2bf(hi) << 16);
}

// ---- fused normalize_adj + sparse row gather ------------------------------
struct AmulSM {
    float vv[256];
    int   jj[256];
    float part[4];
    int   wcnt[4];
    int   woff[4];
    float sinv;
    int   n0;
};

__device__ __forceinline__ void amul_body(const float* __restrict__ adj,
                                          const float* __restrict__ H,
                                          uint16_t* __restrict__ outp,
                                          int b, int i, int tid, AmulSM* sm)
{
    const float* A = adj + ((size_t)b << 16);
    float aij = A[(i << 8) + tid];
    float aji = A[(tid << 8) + i];
    float v = fmaxf(aij, aji);
    if (tid == i) v += 1.0f;

    float s = v;
    #pragma unroll
    for (int off = 32; off > 0; off >>= 1) s += __shfl_down(s, off);

    bool pred = v != 0.0f;
    unsigned long long m = __ballot(pred);
    int wid = tid >> 6;
    if ((tid & 63) == 0) { sm->part[wid] = s; sm->wcnt[wid] = (int)__popcll(m); }
    __syncthreads();
    if (tid == 0) {
        float t = sm->part[0] + sm->part[1] + sm->part[2] + sm->part[3];
        sm->sinv = t > 0.0f ? 1.0f / t : 0.0f;
        int o = 0;
        #pragma unroll
        for (int w = 0; w < 4; ++w) { sm->woff[w] = o; o += sm->wcnt[w]; }
        sm->n0 = o;
    }
    __syncthreads();
    if (pred) {
        int pos = sm->woff[wid] + (int)__popcll(m & ((1ull << (tid & 63)) - 1ull));
        sm->vv[pos] = v * sm->sinv;
        sm->jj[pos] = tid;
    }
    __syncthreads();

    const int n0 = sm->n0;
    const int f0 = tid * 8;
    const float* Hb = H + (((size_t)b) << 8) * 2048;
    float acc[8] = {};
    for (int c = 0; c < n0; ++c) {
        float av = sm->vv[c];
        const float* hp = Hb + (size_t)sm->jj[c] * 2048 + f0;
        float4 p = *(const float4*)hp;
        float4 q = *(const float4*)(hp + 4);
        acc[0] += av * p.x; acc[1] += av * p.y; acc[2] += av * p.z; acc[3] += av * p.w;
        acc[4] += av * q.x; acc[5] += av * q.y; acc[6] += av * q.z; acc[7] += av * q.w;
    }
    uint4 o;
    o.x = f2bf2(acc[0], acc[1]);
    o.y = f2bf2(acc[2], acc[3]);
    o.z = f2bf2(acc[4], acc[5]);
    o.w = f2bf2(acc[6], acc[7]);
    *(uint4*)(outp + (((size_t)b << 8) + i) * 2048 + f0) = o;
}

// XCD-swizzled (b,i): XCD x (=bid%8) keeps one batch's H (2MB) L2-resident
__device__ __forceinline__ void amul_swizzle(int bid, int& b, int& i) {
    int x = bid & 7, g = bid >> 3;
    b = x >> 1;
    i = ((x & 1) << 7) + g;
}

// ---- dispatch 1: amul#1 | wT | W1/W2-transpose | pad_x (inputs only) ------
#define PR_AM 1024
#define PR_W  3072
#define PR_T  5120
#define PR_N  17456

__global__ __launch_bounds__(256)
void k_prep(const float* __restrict__ x, uint16_t* __restrict__ xpad,
            const float* __restrict__ w, uint16_t* __restrict__ wT,
            const float* __restrict__ W1, const float* __restrict__ W2,
            uint16_t* __restrict__ W1T, uint16_t* __restrict__ W2T,
            const float* __restrict__ adj, const float* __restrict__ nodes,
            uint16_t* __restrict__ gbf)
{
    __shared__ union {
        float  wbuf[6144];
        float  tile[64][65];
        AmulSM am;
    } sm;
    const int bid = blockIdx.x;
    const int tid = threadIdx.x;

    if (bid < PR_AM) {
        int b, i; amul_swizzle(bid, b, i);
        amul_body(adj, nodes, gbf, b, i, tid, &sm.am);
    } else if (bid < PR_W) {
        // conv_w [o][i][h] -> wT [o][h*2048+i] bf16 (LDS-staged)
        int o = bid - PR_AM;
        const float* src = w + (size_t)o * 6144;
        uint16_t*    dst = wT + (size_t)o * 6144;
        #pragma unroll
        for (int it = 0; it < 24; ++it)
            sm.wbuf[it * 256 + tid] = src[it * 256 + tid];
        __syncthreads();
        #pragma unroll
        for (int h = 0; h < 3; ++h)
            #pragma unroll
            for (int c = 0; c < 8; ++c) {
                int i = c * 256 + tid;
                dst[h * 2048 + i] = f2bf(sm.wbuf[i * 3 + h]);   // stride-3: conflict-free
            }
    } else if (bid < PR_T) {
        // W1/W2 [2048][2048] -> bf16 transpose
        int t  = bid - PR_W;
        int z  = t >> 10;
        int by = (t >> 5) & 31;
        int bx = t & 31;
        const float* src = z ? W2 : W1;
        uint16_t*    dst = z ? W2T : W1T;
        int tx = tid & 63, ty = tid >> 6;
        for (int rr = ty; rr < 64; rr += 4)
            sm.tile[rr][tx] = src[(size_t)(by * 64 + rr) * 2048 + bx * 64 + tx];
        __syncthreads();
        for (int rr = ty; rr < 64; rr += 4)
            dst[(size_t)(bx * 64 + rr) * 2048 + by * 64 + tx] = f2bf(sm.tile[tx][rr]);
    } else {
        // x [12,512,2048] f32 -> xpad [12,514,2048] bf16, 4 elems/thread
        int idx4 = (bid - PR_T) * 256 + tid;       // < 3,158,016
        int ch4  = idx4 & 511;
        int tmp  = idx4 >> 9;                      // b*514 + tt
        int b    = tmp / 514;
        int tt   = tmp - b * 514;
        float4 v = {0.0f, 0.0f, 0.0f, 0.0f};
        if (tt >= 1 && tt <= 512)
            v = *(const float4*)(x + ((size_t)(b * 512 + tt - 1) << 11) + ch4 * 4);
        uint2 o = { f2bf2(v.x, v.y), f2bf2(v.z, v.w) };
        ((uint2*)xpad)[idx4] = o;
    }
}

// ---- 128x128 GEMM tile (m97-class), BK=64, swizzled 64B-row LDS -----------
// (verified rounds 4/5)
template<bool RELU>
__device__ __forceinline__ void g128_tile(char* lds, const uint16_t* __restrict__ A,
                                          const uint16_t* __restrict__ BT,
                                          float* __restrict__ C, const float* __restrict__ bias,
                                          int rt, int ct, int tid)
{
    char* As = lds;
    char* Bs = lds + 16384;
    const int lane = tid & 63, wave = tid >> 6;
    const int wm = (wave >> 1) * 64, wn = (wave & 1) * 64;
    const int lm = lane & 15, lq = lane >> 4;
    const int abyte = (wm + lm) * 64 + ((lq * 16) ^ ((lm & 3) << 4));
    const int bbyte = (wn + lm) * 64 + ((lq * 16) ^ ((lm & 3) << 4));

    int soff[4];
    #pragma unroll
    for (int j = 0; j < 4; ++j) {
        int c = tid + 256 * j;                  // 0..1023
        int row = (c >> 2) & 127;
        soff[j] = row * 2048 + ((c >> 9) << 5) + (((c & 3) ^ (row & 3)) << 3);
    }

    floatx4 acc[4][4] = {};
    for (int k0 = 0; k0 < 2048; k0 += 64) {
        #pragma unroll
        for (int j = 0; j < 4; ++j) {
            gload_lds16(A  + (size_t)rt * 2048 + soff[j] + k0, As + tid * 16 + j * 4096);
            gload_lds16(BT + (size_t)ct * 2048 + soff[j] + k0, Bs + tid * 16 + j * 4096);
        }
        __syncthreads();
        #pragma unroll
        for (int s = 0; s < 2; ++s) {
            bf16x8 af[4], bfr[4];
            #pragma unroll
            for (int mt = 0; mt < 4; ++mt)
                af[mt] = *(const bf16x8*)(As + s * 8192 + abyte + mt * 1024);
            #pragma unroll
            for (int nt = 0; nt < 4; ++nt)
                bfr[nt] = *(const bf16x8*)(Bs + s * 8192 + bbyte + nt * 1024);
            #pragma unroll
            for (int mt = 0; mt < 4; ++mt)
                #pragma unroll
                for (int nt = 0; nt < 4; ++nt)
                    acc[mt][nt] = __builtin_amdgcn_mfma_f32_16x16x32_bf16(af[mt], bfr[nt], acc[mt][nt], 0, 0, 0);
        }
        __syncthreads();
    }

    #pragma unroll
    for (int mt = 0; mt < 4; ++mt)
        #pragma unroll
        for (int nt = 0; nt < 4; ++nt) {
            int col = ct + wn + nt * 16 + lm;
            float bv = bias[col];
            #pragma unroll
            for (int r = 0; r < 4; ++r) {
                int row = rt + wm + mt * 16 + lq * 4 + r;
                float v = acc[mt][nt][r] + bv;
                if (RELU) v = fmaxf(v, 0.0f);
                C[(size_t)row * 2048 + col] = v;
            }
        }
}

// ===========================================================================
// conv GEMM: r3 pipeline (192x256 tile, BK=32, 4-deep ring, counted vmcnt(6),
// identical staging/swizzle) but 32x32x16 MFMA and ONE phase per window:
//   {10 ds_read_b128 | 7 gload_lds -> barrier -> lgkm(0) -> 12 MFMA ->
//    vmcnt(6) -> barrier}   (2 barriers/window instead of 4)
// Frag reads verified bank-minimal under the r1 swizzle (8 words/bank).
// ===========================================================================
template<int BUF, bool STG, int VN>
__device__ __forceinline__ void conv_win(char* ldsb, int tid,
    const uint16_t*& aS0, const uint16_t*& aS1,
    const uint16_t*& bS0, const uint16_t*& bS1,
    const int (&arow)[3], const int (&brow)[2], const int (&kso)[2],
    floatx16 (&acc)[3][2])
{
    char* As  = ldsb + BUF * 12288;
    char* Bs  = ldsb + 49152 + BUF * 16384;
    constexpr int NB = (BUF + 3) & 3;
    char* As3 = ldsb + NB * 12288;
    char* Bs3 = ldsb + 49152 + NB * 16384;

    bf16x8 av[3][2], bv[2][2];
    #pragma unroll
    for (int fm = 0; fm < 3; ++fm)
        #pragma unroll
        for (int s = 0; s < 2; ++s)
            av[fm][s] = *(const bf16x8*)(As + arow[fm] + kso[s]);
    #pragma unroll
    for (int fn = 0; fn < 2; ++fn)
        #pragma unroll
        for (int s = 0; s < 2; ++s)
            bv[fn][s] = *(const bf16x8*)(Bs + brow[fn] + kso[s]);

    if constexpr (STG) {
        gload_lds16(aS0, As3 + tid * 16); aS0 += 32;
        if (tid < 256) { gload_lds16(aS1, As3 + 8192 + tid * 16); aS1 += 32; }
        gload_lds16(bS0, Bs3 + tid * 16); bS0 += 32;
        gload_lds16(bS1, Bs3 + 8192 + tid * 16); bS1 += 32;
    }
    SB0;
    __builtin_amdgcn_s_barrier();
    asm volatile("s_waitcnt lgkmcnt(0)");
    SB0;
    __builtin_amdgcn_s_setprio(1);
    #pragma unroll
    for (int fm = 0; fm < 3; ++fm)
        #pragma unroll
        for (int fn = 0; fn < 2; ++fn)
            #pragma unroll
            for (int s = 0; s < 2; ++s)
                acc[fm][fn] = __builtin_amdgcn_mfma_f32_32x32x16_bf16(
                    av[fm][s], bv[fn][s], acc[fm][fn], 0, 0, 0);
    __builtin_amdgcn_s_setprio(0);
    SB0;
    if constexpr (VN >= 0) asm volatile("s_waitcnt vmcnt(%0)" :: "i"(VN));
    SB0;
    __builtin_amdgcn_s_barrier();
    SB0;
}

// ---- dispatch 2: conv GEMM (256 blocks) then gemm128#1 (64 blocks x 2) ----
__global__ __launch_bounds__(512, 2)
void k_big(const uint16_t* __restrict__ xpad, const uint16_t* __restrict__ wmT,
           float* __restrict__ feats, const float* __restrict__ conv_b,
           const uint16_t* __restrict__ gbf, const uint16_t* __restrict__ W1T,
           float* __restrict__ h, const float* __restrict__ b1)
{
    __shared__ __align__(16) char smem[114688];
    const int bid = blockIdx.x;
    const int tid = threadIdx.x;

    if (bid < 256) {
        // -------- conv: 192x256 tile, XCD-swizzled (256 % 8 == 0) ----------
        const int xcd  = bid & 7;
        const int gg   = bid >> 3;                 // 0..31
        const int tile = xcd * 32 + gg;
        const int rt   = (tile >> 3) * 192;        // 0..5952
        const int ct   = (tile & 7) * 256;         // 0..1792

        const int lane = tid & 63, wave = tid >> 6;
        const int mw = wave >> 2, nw = wave & 3;
        const int l31 = lane & 31;
        const int lk  = (lane >> 5) * 16;
        const int xv  = (l31 & 3) << 4;            // row&3 == l31&3
        int arow[3], brow[2], kso[2];
        kso[0] = lk ^ xv;
        kso[1] = (32 + lk) ^ xv;
        #pragma unroll
        for (int fm = 0; fm < 3; ++fm) arow[fm] = (mw * 96 + fm * 32 + l31) * 64;
        #pragma unroll
        for (int fn = 0; fn < 2; ++fn) brow[fn] = (nw * 64 + fn * 32 + l31) * 64;

        // staging constants (identical to r1/r3):
        const int c1  = 512 + tid;
        const int r0  = tid >> 2,  kc0 = ((tid & 3) ^ (r0 & 3)) * 8;
        const int r1  = c1 >> 2,   kc1 = ((c1 & 3) ^ (r1 & 3)) * 8;

        const int RA0 = rt + r0;
        const int RA1 = rt + r1;   // only dereferenced when tid<256 (r1<192)
        const uint16_t* aS0 = xpad + (((size_t)((RA0 >> 9) * 514 + (RA0 & 511))) << 11) + kc0;
        const uint16_t* aS1 = xpad + (((size_t)((RA1 >> 9) * 514 + (RA1 & 511))) << 11) + kc1;
        const uint16_t* bS0 = wmT + (size_t)(ct + r0) * 6144 + kc0;
        const uint16_t* bS1 = wmT + (size_t)(ct + r1) * 6144 + kc1;

        // prologue: stage K-tiles 0,1,2 (keep 6 loads in flight)
        #pragma unroll
        for (int p = 0; p < 3; ++p) {
            char* As3 = smem + p * 12288;
            char* Bs3 = smem + 49152 + p * 16384;
            gload_lds16(aS0, As3 + tid * 16); aS0 += 32;
            if (tid < 256) { gload_lds16(aS1, As3 + 8192 + tid * 16); aS1 += 32; }
            gload_lds16(bS0, Bs3 + tid * 16); bS0 += 32;
            gload_lds16(bS1, Bs3 + 8192 + tid * 16); bS1 += 32;
        }
        SB0;
        asm volatile("s_waitcnt vmcnt(6)");   // tile 0 landed; 1,2 in flight
        SB0;
        __builtin_amdgcn_s_barrier();
        SB0;

        floatx16 acc[3][2] = {};
        // windows 0..187 (stage tiles 3..190), vmcnt(6) once per window
        #pragma unroll 1
        for (int it = 0; it < 47; ++it) {
            conv_win<0, true, 6>(smem, tid, aS0, aS1, bS0, bS1, arow, brow, kso, acc);
            conv_win<1, true, 6>(smem, tid, aS0, aS1, bS0, bS1, arow, brow, kso, acc);
            conv_win<2, true, 6>(smem, tid, aS0, aS1, bS0, bS1, arow, brow, kso, acc);
            conv_win<3, true, 6>(smem, tid, aS0, aS1, bS0, bS1, arow, brow, kso, acc);
        }
        // epilogue: w=188 stages tile 191; then drain 6 -> 3 -> 0
        conv_win<0, true,  6>(smem, tid, aS0, aS1, bS0, bS1, arow, brow, kso, acc);
        conv_win<1, false, 3>(smem, tid, aS0, aS1, bS0, bS1, arow, brow, kso, acc);
        conv_win<2, false, 0>(smem, tid, aS0, aS1, bS0, bS1, arow, brow, kso, acc);
        conv_win<3, false,-1>(smem, tid, aS0, aS1, bS0, bS1, arow, brow, kso, acc);

        // C write: 32x32 frag layout col=lane&31, row=(r&3)+8*(r>>2)+4*(lane>>5)
        const int rhi = (lane >> 5) * 4;
        #pragma unroll
        for (int fm = 0; fm < 3; ++fm)
            #pragma unroll
            for (int fn = 0; fn < 2; ++fn) {
                int col = ct + nw * 64 + fn * 32 + l31;
                float bb = conv_b[col];
                #pragma unroll
                for (int r = 0; r < 16; ++r) {
                    int row = rt + mw * 96 + fm * 32 + (r & 3) + 8 * (r >> 2) + rhi;
                    feats[(size_t)row * 2048 + col] = fmaxf(acc[fm][fn][r] + bb, 0.0f);
                }
            }
    } else {
        // -------- gemm128#1: h = relu(gbf @ W1T^T + b1), 2 tiles/block -----
        const int t    = bid - 256;            // 0..63
        const int half = tid >> 8;
        const int st   = t * 2 + half;         // 0..127
        const int idx  = (st & 7) * 16 + (st >> 3);   // XCD swizzle
        const int rt   = (idx & 7) * 128;      // M=1024
        const int ct   = (idx >> 3) * 128;     // N=2048
        g128_tile<true>(smem + half * 32768, gbf, W1T, h, b1, rt, ct, tid & 255);
    }
}

// ---- dispatch 3: ahb = a @ h (bf16), normalize folded in, XCD-swizzled ----
__global__ __launch_bounds__(256)
void k_amul(const float* __restrict__ adj, const float* __restrict__ H,
            uint16_t* __restrict__ outp)
{
    __shared__ AmulSM sm;
    int b, i; amul_swizzle(blockIdx.x, b, i);
    amul_body(adj, H, outp, b, i, threadIdx.x, &sm);
}

// ---- dispatch 4: out = ahb @ W2T^T + b2, 128x128 tiles, XCD-swizzled ------
__global__ __launch_bounds__(256)
void k_gemm64(const uint16_t* __restrict__ A, const uint16_t* __restrict__ BT,
              float* __restrict__ C, const float* __restrict__ bias)
{
    __shared__ __align__(16) char lds[32768];
    const int bid = blockIdx.x;                    // 0..127
    const int idx = (bid & 7) * 16 + (bid >> 3);
    const int rt  = (idx & 7) * 128;
    const int ct  = (idx >> 3) * 128;
    g128_tile<false>(lds, A, BT, C, bias, rt, ct, threadIdx.x);
}

// ---- launch ---------------------------------------------------------------

extern "C" void kernel_launch(void* const* d_in, const int* in_sizes, int n_in,
                              void* d_out, int out_size, void* d_ws, size_t ws_size,
                              hipStream_t stream)
{
    const float* x      = (const float*)d_in[0];
    const float* nodes  = (const float*)d_in[1];
    const float* adj    = (const float*)d_in[2];
    const float* conv_w = (const float*)d_in[3];
    const float* conv_b = (const float*)d_in[4];
    const float* W1     = (const float*)d_in[5];
    const float* b1     = (const float*)d_in[6];
    const float* W2     = (const float*)d_in[7];
    const float* b2     = (const float*)d_in[8];
    float* out = (float*)d_out;

    char* ws = (char*)d_ws;
    uint16_t* xpad   = (uint16_t*)(ws);                 // 25,288,704
    uint16_t* wmT    = (uint16_t*)(ws + 25288704);      // 25,165,824
    uint16_t* W1T    = (uint16_t*)(ws + 50454528);      // 8,388,608
    uint16_t* W2T    = (uint16_t*)(ws + 58843136);      // 8,388,608
    uint16_t* gbf    = (uint16_t*)(ws + 67231744);      // 4,194,304  a@nodes (bf16)
    float*    h      = (float*)   (ws + 71426048);      // 8,388,608  relu(gbf@W1+b1)
    uint16_t* ahb    = (uint16_t*)(ws + 79814656);      // 4,194,304  a@h (bf16)

    // d1: everything that depends only on inputs
    k_prep<<<PR_N, 256, 0, stream>>>(x, xpad, conv_w, wmT,
                                     W1, W2, W1T, W2T, adj, nodes, gbf);
    // d2: conv GEMM (32x32 MFMA, 1-phase windows) then gemm128#1 tail
    k_big<<<320, 512, 0, stream>>>(xpad, wmT, out, conv_b, gbf, W1T, h, b1);
    // d3: ahb = a @ h
    k_amul<<<1024, 256, 0, stream>>>(adj, h, ahb);
    // d4: out_gcn = ahb @ W2 + b2
    k_gemm64<<<128, 256, 0, stream>>>(ahb, W2T, out + 12582912, b2);
}